// Round 5
// baseline (969.526 us; speedup 1.0000x reference)
//
#include <hip/hip_runtime.h>

constexpr int N_NODES  = 500000;
constexpr int N_EDGES  = 8000000;
constexpr int N_GRAPHS = 25000;
constexpr int HID      = 19;

constexpr int NC    = (N_NODES + 1023) / 1024;   // 489 coarse buckets (dst>>10)
constexpr int P1B   = 256;                       // histogram blocks
constexpr int CHUNK = 8192;                      // edges per p2 block
constexpr int P2B   = (N_EDGES + CHUNK - 1) / CHUNK;  // 977
constexpr int NPB   = 26;                        // nodes per 512-thread layer block (26*19=494)

// ---------------- prep: pad x (11ch,44B) -> xp (16ch,64B rows) + pos ----------------
__global__ __launch_bounds__(256)
void prep_kernel(const float* __restrict__ x, float* __restrict__ xp,
                 const int* __restrict__ batch, int* __restrict__ pos) {
    int i = blockIdx.x * 256 + threadIdx.x;
    if (i >= N_NODES) return;
    int b  = batch[i];
    int nb = (i == N_NODES - 1) ? N_GRAPHS : batch[i + 1];
    for (int g = b; g < nb; ++g) pos[g] = i;
    if (i == 0) {
        for (int g = 0; g < b; ++g) pos[g] = N_NODES - 1;   // JAX -1 wrap
    }
    const float* xs = x + (size_t)i * 11;
    float* xd = xp + (size_t)i * 16;
    #pragma unroll
    for (int k = 0; k < 11; ++k) xd[k] = xs[k];
}

// ---------------- P1: per-block coarse histograms ----------------
__global__ __launch_bounds__(256)
void p1_hist(const int* __restrict__ dst, int* __restrict__ blockhist) {
    __shared__ int h[NC];
    int t = threadIdx.x;
    for (int i = t; i < NC; i += 256) h[i] = 0;
    __syncthreads();
    int per = (N_EDGES + P1B - 1) / P1B;
    int s0 = blockIdx.x * per;
    int s1 = min(s0 + per, N_EDGES);
    for (int e = s0 + t; e < s1; e += 256) atomicAdd(&h[dst[e] >> 10], 1);
    __syncthreads();
    for (int i = t; i < NC; i += 256) blockhist[blockIdx.x * NC + i] = h[i];
}

// ---------------- K2a: column totals (one block per coarse bucket) ----------------
__global__ __launch_bounds__(64)
void k2a_colsum(const int* __restrict__ blockhist, int* __restrict__ coltotal) {
    __shared__ int sh[64];
    int c = blockIdx.x, t = threadIdx.x;
    int s = 0;
    for (int b = t; b < P1B; b += 64) s += blockhist[b * NC + c];
    sh[t] = s;
    __syncthreads();
    for (int off = 32; off > 0; off >>= 1) {
        if (t < off) sh[t] += sh[t + off];
        __syncthreads();
    }
    if (t == 0) coltotal[c] = sh[0];
}

// ---------------- K2b: scan coarse totals ----------------
__global__ __launch_bounds__(512)
void k2b_scan(const int* __restrict__ coltotal, int* __restrict__ coarse_off,
              int* __restrict__ cursor, int* __restrict__ offsets) {
    __shared__ int sh[512];
    int t = threadIdx.x;
    int s = (t < NC) ? coltotal[t] : 0;
    sh[t] = s;
    for (int off = 1; off < 512; off <<= 1) {
        __syncthreads();
        int a = (t >= off) ? sh[t - off] : 0;
        __syncthreads();
        sh[t] += a;
    }
    __syncthreads();
    if (t < NC) { int excl = sh[t] - s; coarse_off[t] = excl; cursor[t] = excl; }
    if (t == 0) { coarse_off[NC] = N_EDGES; offsets[N_NODES] = N_EDGES; }
}

// ---------------- P2: chunked scatter into coarse buckets ----------------
// pack = src | (dst&1023)<<19
__global__ __launch_bounds__(256)
void p2_scatter(const int* __restrict__ src, const int* __restrict__ dst,
                int* __restrict__ cursor, int* __restrict__ bc) {
    __shared__ int h[NC], base[NC];
    int t = threadIdx.x;
    for (int i = t; i < NC; i += 256) h[i] = 0;
    __syncthreads();
    int e0 = blockIdx.x * CHUNK;
    int e1 = min(e0 + CHUNK, N_EDGES);
    for (int e = e0 + t; e < e1; e += 256) atomicAdd(&h[dst[e] >> 10], 1);
    __syncthreads();
    for (int i = t; i < NC; i += 256) {
        int c = h[i];
        base[i] = c ? atomicAdd(&cursor[i], c) : 0;
    }
    __syncthreads();
    for (int i = t; i < NC; i += 256) h[i] = 0;
    __syncthreads();
    for (int e = e0 + t; e < e1; e += 256) {
        int d = dst[e];
        int cb = d >> 10;
        int r = atomicAdd(&h[cb], 1);
        bc[base[cb] + r] = src[e] | ((d & 1023) << 19);
    }
}

// ---------------- P3: node-exact CSR within each coarse bucket ----------------
__global__ __launch_bounds__(256)
void p3_csr(const int* __restrict__ coarse_off, const int* __restrict__ bc,
            int* __restrict__ offsets, int* __restrict__ csr) {
    int c = blockIdx.x;
    int b0 = coarse_off[c], b1 = coarse_off[c + 1];
    __shared__ int h[1024], cur[1024], ts[256];
    int t = threadIdx.x;
    for (int i = t; i < 1024; i += 256) h[i] = 0;
    __syncthreads();
    for (int i = b0 + t; i < b1; i += 256) atomicAdd(&h[(bc[i] >> 19) & 1023], 1);
    __syncthreads();
    int base4 = t * 4;
    int a0 = h[base4], a1 = h[base4 + 1], a2 = h[base4 + 2], a3 = h[base4 + 3];
    int s = a0 + a1 + a2 + a3;
    ts[t] = s;
    for (int off = 1; off < 256; off <<= 1) {
        __syncthreads();
        int v = (t >= off) ? ts[t - off] : 0;
        __syncthreads();
        ts[t] += v;
    }
    __syncthreads();
    int excl = ts[t] - s;
    h[base4]     = excl;
    h[base4 + 1] = excl + a0;
    h[base4 + 2] = excl + a0 + a1;
    h[base4 + 3] = excl + a0 + a1 + a2;
    cur[base4]     = h[base4];
    cur[base4 + 1] = h[base4 + 1];
    cur[base4 + 2] = h[base4 + 2];
    cur[base4 + 3] = h[base4 + 3];
    __syncthreads();
    int node0 = c << 10;
    for (int i = t; i < 1024; i += 256) {
        int n = node0 + i;
        if (n < N_NODES) offsets[n] = b0 + h[i];
    }
    for (int i = b0 + t; i < b1; i += 256) {
        int v = bc[i];
        int loc = (v >> 19) & 1023;
        int p = atomicAdd(&cur[loc], 1);
        csr[b0 + p] = v & 0x7FFFF;
    }
}

// ---------------- combined weights: wc = w0 @ w1[IN:], db = b0 @ w1[IN:] ----------------
__global__ __launch_bounds__(256)
void weights_kernel(const float* w0_1, const float* b0_1, const float* w1_1,
                    const float* w0_2, const float* b0_2, const float* w1_2,
                    const float* w0_3, const float* b0_3, const float* w1_3,
                    float* __restrict__ out) {
    const float *w0, *b0, *w1; int IN;
    if (blockIdx.x == 0)      { w0 = w0_1; b0 = b0_1; w1 = w1_1; IN = 11; }
    else if (blockIdx.x == 1) { w0 = w0_2; b0 = b0_2; w1 = w1_2; IN = 19; }
    else                      { w0 = w0_3; b0 = b0_3; w1 = w1_3; IN = 19; }
    __shared__ float sw0[19 * 19], sw1b[19 * 19], sb0[19];
    int t = threadIdx.x;
    for (int i = t; i < IN * 19; i += 256) sw0[i]  = w0[i];
    for (int i = t; i < 19 * 19; i += 256) sw1b[i] = w1[IN * 19 + i];
    if (t < 19) sb0[t] = b0[t];
    __syncthreads();
    float* o = out + blockIdx.x * 380;
    for (int idx = t; idx < IN * 19; idx += 256) {
        int i = idx / 19, j = idx - 19 * (idx / 19);
        float s = 0.f;
        #pragma unroll
        for (int k = 0; k < 19; ++k) s = fmaf(sw0[i * 19 + k], sw1b[k * 19 + j], s);
        o[idx] = s;
    }
    if (t < 19) {
        float s = 0.f;
        #pragma unroll
        for (int k = 0; k < 19; ++k) s = fmaf(sb0[k], sw1b[k * 19 + t], s);
        o[361 + t] = s;
    }
}

// ---------------- fused layer: out = relu(x@w1a + (S@xg)@wc + deg*db + b1 [+ x]) ----------------
// IN = input channels, GS = gather row stride (floats), xg = gather source
template<int IN, int GS, bool RES>
__global__ __launch_bounds__(512)
void fused_layer(const float* __restrict__ x, const float* __restrict__ xg,
                 const int* __restrict__ csr, const int* __restrict__ offsets,
                 const float* __restrict__ w1, const float* __restrict__ b1,
                 const float* __restrict__ wcdb, float* __restrict__ out) {
    __shared__ float sw1a[IN * 19], swc[IN * 19], sdb[19], sb1[19];
    __shared__ float shx[NPB][19], shs[NPB][19];
    int t = threadIdx.x;
    for (int i = t; i < IN * 19; i += 512) sw1a[i] = w1[i];
    for (int i = t; i < IN * 19; i += 512) swc[i]  = wcdb[i];
    if (t < 19) { sdb[t] = wcdb[361 + t]; sb1[t] = b1[t]; }
    __syncthreads();
    int g = t / 19, c = t - g * 19;
    int n = blockIdx.x * NPB + g;
    bool active = (t < NPB * 19) && (n < N_NODES);
    int o0 = 0, o1 = 0;
    if (active) {
        o0 = offsets[n]; o1 = offsets[n + 1];
        float xr = 0.f, acc = 0.f;
        if (c < IN) {
            xr = x[(size_t)n * IN + c];
            int i = o0;
            for (; i + 3 < o1; i += 4) {
                int s0 = __builtin_nontemporal_load(csr + i);
                int s1 = __builtin_nontemporal_load(csr + i + 1);
                int s2 = __builtin_nontemporal_load(csr + i + 2);
                int s3 = __builtin_nontemporal_load(csr + i + 3);
                float v0 = xg[(size_t)s0 * GS + c];
                float v1 = xg[(size_t)s1 * GS + c];
                float v2 = xg[(size_t)s2 * GS + c];
                float v3 = xg[(size_t)s3 * GS + c];
                acc += (v0 + v1) + (v2 + v3);
            }
            for (; i < o1; ++i) {
                int s0 = __builtin_nontemporal_load(csr + i);
                acc += xg[(size_t)s0 * GS + c];
            }
        }
        shx[g][c] = xr; shs[g][c] = acc;
    }
    __syncthreads();
    if (active) {
        float v = sb1[c] + (float)(o1 - o0) * sdb[c];
        #pragma unroll
        for (int i = 0; i < IN; ++i) v = fmaf(shx[g][i], sw1a[i * 19 + c], v);
        #pragma unroll
        for (int i = 0; i < IN; ++i) v = fmaf(shs[g][i], swc[i * 19 + c], v);
        if (RES) v += shx[g][c];
        out[(size_t)n * 19 + c] = fmaxf(v, 0.f);
    }
}

// ---------------- readout ----------------
__global__ __launch_bounds__(256)
void readout_kernel(const float* __restrict__ h, const int* __restrict__ pos,
                    const float* __restrict__ w0, const float* __restrict__ b0,
                    const float* __restrict__ w1, const float* __restrict__ b1,
                    float* __restrict__ out) {
    __shared__ float ws[HID * 10 + 10 + 10 + 1];
    for (int i = threadIdx.x; i < 211; i += 256) {
        float v;
        if (i < 190)      v = w0[i];
        else if (i < 200) v = b0[i - 190];
        else if (i < 210) v = w1[i - 200];
        else              v = b1[0];
        ws[i] = v;
    }
    __syncthreads();
    int g = blockIdx.x * 256 + threadIdx.x;
    if (g >= N_GRAPHS) return;
    const float* hp = h + (size_t)pos[g] * HID;
    float t[10];
    #pragma unroll
    for (int j = 0; j < 10; ++j) {
        float acc = ws[190 + j];
        #pragma unroll
        for (int i = 0; i < HID; ++i) acc = fmaf(hp[i], ws[i * 10 + j], acc);
        t[j] = fmaxf(acc, 0.0f);
    }
    float o = ws[210];
    #pragma unroll
    for (int j = 0; j < 10; ++j) o = fmaf(t[j], ws[200 + j], o);
    out[g] = fmaxf(o, 0.0f);
}

extern "C" void kernel_launch(void* const* d_in, const int* in_sizes, int n_in,
                              void* d_out, int out_size, void* d_ws, size_t ws_size,
                              hipStream_t stream) {
    const float* x     = (const float*)d_in[0];
    const int*   ei    = (const int*)d_in[1];
    const int*   batch = (const int*)d_in[2];
    const float* w0_1 = (const float*)d_in[3];
    const float* b0_1 = (const float*)d_in[4];
    const float* w1_1 = (const float*)d_in[5];
    const float* b1_1 = (const float*)d_in[6];
    const float* w0_2 = (const float*)d_in[7];
    const float* b0_2 = (const float*)d_in[8];
    const float* w1_2 = (const float*)d_in[9];
    const float* b1_2 = (const float*)d_in[10];
    const float* w0_3 = (const float*)d_in[11];
    const float* b0_3 = (const float*)d_in[12];
    const float* w1_3 = (const float*)d_in[13];
    const float* b1_3 = (const float*)d_in[14];
    const float* wfc0 = (const float*)d_in[15];
    const float* bfc0 = (const float*)d_in[16];
    const float* wfc1 = (const float*)d_in[17];
    const float* bfc1 = (const float*)d_in[18];

    const int* src = ei;            // edge_index[0]
    const int* dst = ei + N_EDGES;  // edge_index[1]

    char* ws = (char*)d_ws;
    size_t off = 0;
    auto alloc = [&](size_t bytes) { void* p = ws + off; off = (off + bytes + 511) & ~(size_t)511; return p; };
    float* BUF_A     = (float*)alloc((size_t)N_NODES * HID * 4);   // 38 MB
    float* BUF_B     = (float*)alloc((size_t)N_NODES * 16  * 4);   // 32 MB (also padded x alias)
    int*   csr       = (int*)  alloc((size_t)N_EDGES * 4);         // 32 MB
    int*   offsets   = (int*)  alloc(((size_t)N_NODES + 1) * 4);
    int*   blockhist = (int*)  alloc((size_t)P1B * NC * 4);        // 0.5 MB
    int*   coarse_off= (int*)  alloc((NC + 1) * 4);
    int*   cursor    = (int*)  alloc(NC * 4);
    int*   coltotal  = (int*)  alloc(NC * 4);
    int*   pos       = (int*)  alloc((size_t)N_GRAPHS * 4);
    float* wcdb      = (float*)alloc(3 * 380 * 4);
    // aliases: bc (coarse packs) dead before layer1 writes BUF_A;
    // xp (padded x) dead before layer2 writes BUF_B
    int*   bc        = (int*)BUF_A;
    float* xp        = (float*)BUF_B;
    // NOTE: BUF_B only holds 16 floats/node; layers writing 19 floats/node need
    // BUF_A (19) and a separate 19-wide buffer for layer2 output:
    float* BUF_C     = (float*)alloc((size_t)N_NODES * HID * 4);   // 38 MB (layer2 out)

    dim3 blk(256);
    int gridN = (N_NODES + 255) / 256;
    int gridF = (N_NODES + NPB - 1) / NPB;   // 19231 blocks of 512
    int gridG = (N_GRAPHS + 255) / 256;

    weights_kernel<<<3, blk, 0, stream>>>(w0_1, b0_1, w1_1, w0_2, b0_2, w1_2,
                                          w0_3, b0_3, w1_3, wcdb);
    prep_kernel<<<gridN, blk, 0, stream>>>(x, xp, batch, pos);

    // ---- bucket sort -> node-exact CSR ----
    p1_hist<<<P1B, blk, 0, stream>>>(dst, blockhist);
    k2a_colsum<<<NC, 64, 0, stream>>>(blockhist, coltotal);
    k2b_scan<<<1, 512, 0, stream>>>(coltotal, coarse_off, cursor, offsets);
    p2_scatter<<<P2B, blk, 0, stream>>>(src, dst, cursor, bc);
    p3_csr<<<NC, blk, 0, stream>>>(coarse_off, bc, offsets, csr);

    // ---- 3 fused layers ----
    // L1: self = x (11ch packed), gather = xp (stride 16, 64B rows) -> BUF_A
    fused_layer<11, 16, false><<<gridF, 512, 0, stream>>>(x,     xp,    csr, offsets, w1_1, b1_1, wcdb,       BUF_A);
    // L2: self = gather = BUF_A (19) -> BUF_C
    fused_layer<19, 19, true ><<<gridF, 512, 0, stream>>>(BUF_A, BUF_A, csr, offsets, w1_2, b1_2, wcdb + 380, BUF_C);
    // L3: self = gather = BUF_C (19) -> BUF_A
    fused_layer<19, 19, true ><<<gridF, 512, 0, stream>>>(BUF_C, BUF_C, csr, offsets, w1_3, b1_3, wcdb + 760, BUF_A);

    // ---- Readout ----
    readout_kernel<<<gridG, blk, 0, stream>>>(BUF_A, pos, wfc0, bfc0, wfc1, bfc1,
                                              (float*)d_out);
}